// Round 1
// baseline (244.585 us; speedup 1.0000x reference)
//
#include <hip/hip_runtime.h>

// Malvar-He-Cutler demosaic, RGGB, reflect-101 padding, fp32.
// Each thread computes one horizontal pixel pair (even col + odd col) so the
// x-parity is straight-line code; y-parity branch is wave-uniform.

__device__ __forceinline__ int reflect_idx(int i, int n) {
    // jnp.pad mode='reflect': -1 -> 1, -2 -> 2, n -> n-2, n+1 -> n-3
    if (i < 0) i = -i;
    if (i >= n) i = 2 * n - 2 - i;
    return i;
}

__device__ __forceinline__ float clip01(float x) {
    return fminf(fmaxf(x, 0.0f), 1.0f);
}

// v[5][6] neighborhood: rows y-2..y+2, cols x0-2..x0+3. Center col index c (2 or 3).

__device__ __forceinline__ float f_g_at_rb(const float v[5][6], int c) {
    // [[0,0,-1,0,0],[0,0,2,0,0],[-1,2,4,2,-1],[0,0,2,0,0],[0,0,-1,0,0]]/8
    return 0.125f * (4.0f * v[2][c]
                     + 2.0f * (v[1][c] + v[3][c] + v[2][c - 1] + v[2][c + 1])
                     - (v[0][c] + v[4][c] + v[2][c - 2] + v[2][c + 2]));
}

__device__ __forceinline__ float f_rb_at_g_col(const float v[5][6], int c) {
    // [[0,0,.5,0,0],[0,-1,0,-1,0],[-1,4,5,4,-1],[0,-1,0,-1,0],[0,0,.5,0,0]]/8
    return 0.125f * (5.0f * v[2][c]
                     + 4.0f * (v[2][c - 1] + v[2][c + 1])
                     - (v[1][c - 1] + v[1][c + 1] + v[3][c - 1] + v[3][c + 1])
                     - (v[2][c - 2] + v[2][c + 2])
                     + 0.5f * (v[0][c] + v[4][c]));
}

__device__ __forceinline__ float f_rb_at_g_row(const float v[5][6], int c) {
    // [[0,0,-1,0,0],[0,-1,4,-1,0],[.5,0,5,0,.5],[0,-1,4,-1,0],[0,0,-1,0,0]]/8
    return 0.125f * (5.0f * v[2][c]
                     + 4.0f * (v[1][c] + v[3][c])
                     - (v[1][c - 1] + v[1][c + 1] + v[3][c - 1] + v[3][c + 1])
                     - (v[0][c] + v[4][c])
                     + 0.5f * (v[2][c - 2] + v[2][c + 2]));
}

__device__ __forceinline__ float f_rb_at_br(const float v[5][6], int c) {
    // [[0,0,-1.5,0,0],[0,2,0,2,0],[-1.5,0,6,0,-1.5],[0,2,0,2,0],[0,0,-1.5,0,0]]/8
    return 0.125f * (6.0f * v[2][c]
                     + 2.0f * (v[1][c - 1] + v[1][c + 1] + v[3][c - 1] + v[3][c + 1])
                     - 1.5f * (v[0][c] + v[4][c] + v[2][c - 2] + v[2][c + 2]));
}

__global__ __launch_bounds__(256) void demosaic_kernel(
    const float* __restrict__ bayer, float* __restrict__ out, int H, int W) {
    const int Wp = W >> 1;
    const int xp = blockIdx.x * blockDim.x + threadIdx.x;  // pixel-pair index
    const int y  = blockIdx.y;
    const int b  = blockIdx.z;
    if (xp >= Wp) return;

    const int x0 = xp * 2;  // even column of the pair
    const size_t plane = (size_t)H * W;
    const float* src = bayer + (size_t)b * plane;

    int ry[5];
#pragma unroll
    for (int dy = 0; dy < 5; ++dy) ry[dy] = reflect_idx(y - 2 + dy, H);

    float v[5][6];
    if (x0 >= 2 && x0 + 3 < W) {
        // interior: three aligned float2 loads per row
#pragma unroll
        for (int dy = 0; dy < 5; ++dy) {
            const float* row = src + (size_t)ry[dy] * W + (x0 - 2);
            const float2 a = *(const float2*)(row);
            const float2 m = *(const float2*)(row + 2);
            const float2 c = *(const float2*)(row + 4);
            v[dy][0] = a.x; v[dy][1] = a.y;
            v[dy][2] = m.x; v[dy][3] = m.y;
            v[dy][4] = c.x; v[dy][5] = c.y;
        }
    } else {
        // border pairs (first/last in each row): scalar loads with reflect
#pragma unroll
        for (int dy = 0; dy < 5; ++dy) {
            const float* row = src + (size_t)ry[dy] * W;
#pragma unroll
            for (int dx = 0; dx < 6; ++dx)
                v[dy][dx] = row[reflect_idx(x0 - 2 + dx, W)];
        }
    }

    float r0, g0, b0, r1, g1, b1;
    if ((y & 1) == 0) {
        // left pixel = R site, right pixel = Gr site
        r0 = v[2][2];
        g0 = f_g_at_rb(v, 2);
        b0 = f_rb_at_br(v, 2);
        r1 = f_rb_at_g_col(v, 3);
        g1 = v[2][3];
        b1 = f_rb_at_g_row(v, 3);
    } else {
        // left pixel = Gb site, right pixel = B site
        r0 = f_rb_at_g_row(v, 2);
        g0 = v[2][2];
        b0 = f_rb_at_g_col(v, 2);
        r1 = f_rb_at_br(v, 3);
        g1 = f_g_at_rb(v, 3);
        b1 = v[2][3];
    }

    float* o = out + (size_t)b * 3 * plane + (size_t)y * W + x0;
    *(float2*)(o)             = make_float2(clip01(r0), clip01(r1));
    *(float2*)(o + plane)     = make_float2(clip01(g0), clip01(g1));
    *(float2*)(o + 2 * plane) = make_float2(clip01(b0), clip01(b1));
}

extern "C" void kernel_launch(void* const* d_in, const int* in_sizes, int n_in,
                              void* d_out, int out_size, void* d_ws, size_t ws_size,
                              hipStream_t stream) {
    const float* bayer = (const float*)d_in[0];
    float* out = (float*)d_out;

    const int H = 2048, W = 2048;
    const int B = in_sizes[0] / (H * W);

    const int Wp = W >> 1;
    dim3 block(256, 1, 1);
    dim3 grid((Wp + 255) / 256, H, B);
    demosaic_kernel<<<grid, block, 0, stream>>>(bayer, out, H, W);
}

// Round 2
// 168.281 us; speedup vs baseline: 1.4534x; 1.4534x over previous
//
#include <hip/hip_runtime.h>

// Malvar-He-Cutler demosaic, RGGB, reflect-101, fp32.
// One block per image row (256 threads x 8 px = 2048). float4 loads/stores.
// XCD-chunked block swizzle: each XCD gets a contiguous band of rows so the
// 5-row input window stays resident in that XCD's private L2.

__device__ __forceinline__ int reflect_idx(int i, int n) {
    // jnp.pad mode='reflect': -1 -> 1, -2 -> 2, n -> n-2, n+1 -> n-3
    if (i < 0) i = -i;
    if (i >= n) i = 2 * n - 2 - i;
    return i;
}

__device__ __forceinline__ float clip01(float x) {
    return fminf(fmaxf(x, 0.0f), 1.0f);
}

// v[5][12] neighborhood: rows y-2..y+2, cols x0-2..x0+9. Pixel k at col index c=k+2.

__device__ __forceinline__ float f_g_at_rb(const float v[5][12], int c) {
    return 0.125f * (4.0f * v[2][c]
                     + 2.0f * (v[1][c] + v[3][c] + v[2][c - 1] + v[2][c + 1])
                     - (v[0][c] + v[4][c] + v[2][c - 2] + v[2][c + 2]));
}

__device__ __forceinline__ float f_rb_at_g_col(const float v[5][12], int c) {
    return 0.125f * (5.0f * v[2][c]
                     + 4.0f * (v[2][c - 1] + v[2][c + 1])
                     - (v[1][c - 1] + v[1][c + 1] + v[3][c - 1] + v[3][c + 1])
                     - (v[2][c - 2] + v[2][c + 2])
                     + 0.5f * (v[0][c] + v[4][c]));
}

__device__ __forceinline__ float f_rb_at_g_row(const float v[5][12], int c) {
    return 0.125f * (5.0f * v[2][c]
                     + 4.0f * (v[1][c] + v[3][c])
                     - (v[1][c - 1] + v[1][c + 1] + v[3][c - 1] + v[3][c + 1])
                     - (v[0][c] + v[4][c])
                     + 0.5f * (v[2][c - 2] + v[2][c + 2]));
}

__device__ __forceinline__ float f_rb_at_br(const float v[5][12], int c) {
    return 0.125f * (6.0f * v[2][c]
                     + 2.0f * (v[1][c - 1] + v[1][c + 1] + v[3][c - 1] + v[3][c + 1])
                     - 1.5f * (v[0][c] + v[4][c] + v[2][c - 2] + v[2][c + 2]));
}

__global__ __launch_bounds__(256) void demosaic_kernel(
    const float* __restrict__ bayer, float* __restrict__ out, int H, int W) {
    // XCD-chunked swizzle: 8 XCDs, gridDim.x divisible by 8.
    const int bid = blockIdx.x;
    const int chunk = gridDim.x >> 3;
    const int swz = (bid & 7) * chunk + (bid >> 3);
    const int b = swz / H;
    const int y = swz - b * H;

    const int t = threadIdx.x;
    const int x0 = t << 3;  // 8 pixels per thread
    const size_t plane = (size_t)H * W;
    const float* src = bayer + (size_t)b * plane;

    int ry[5];
#pragma unroll
    for (int dy = 0; dy < 5; ++dy) ry[dy] = reflect_idx(y - 2 + dy, H);

    const bool left = (x0 == 0);
    const bool right = (x0 + 8 >= W);
    const int xl = left ? 0 : x0 - 4;
    const int xr = right ? W - 4 : x0 + 8;

    float v[5][12];
#pragma unroll
    for (int dy = 0; dy < 5; ++dy) {
        const float* row = src + (size_t)ry[dy] * W;
        const float4 L = *(const float4*)(row + xl);
        const float4 A = *(const float4*)(row + x0);
        const float4 Bv = *(const float4*)(row + x0 + 4);
        const float4 R = *(const float4*)(row + xr);
        v[dy][2] = A.x;  v[dy][3] = A.y;  v[dy][4] = A.z;  v[dy][5] = A.w;
        v[dy][6] = Bv.x; v[dy][7] = Bv.y; v[dy][8] = Bv.z; v[dy][9] = Bv.w;
        // reflect-101 at row edges resolved from registers:
        // col -2 -> 2 (A.z), col -1 -> 1 (A.y); col W -> W-2 (Bv.z), W+1 -> W-3 (Bv.y)
        v[dy][0]  = left  ? A.z  : L.z;
        v[dy][1]  = left  ? A.y  : L.w;
        v[dy][10] = right ? Bv.z : R.x;
        v[dy][11] = right ? Bv.y : R.y;
    }

    float r[8], g[8], bb[8];
    if ((y & 1) == 0) {
#pragma unroll
        for (int k = 0; k < 8; k += 2) {
            const int c = k + 2;
            // even col = R site, odd col = Gr site
            r[k]     = v[2][c];
            g[k]     = f_g_at_rb(v, c);
            bb[k]    = f_rb_at_br(v, c);
            r[k + 1] = f_rb_at_g_col(v, c + 1);
            g[k + 1] = v[2][c + 1];
            bb[k + 1] = f_rb_at_g_row(v, c + 1);
        }
    } else {
#pragma unroll
        for (int k = 0; k < 8; k += 2) {
            const int c = k + 2;
            // even col = Gb site, odd col = B site
            r[k]     = f_rb_at_g_row(v, c);
            g[k]     = v[2][c];
            bb[k]    = f_rb_at_g_col(v, c);
            r[k + 1] = f_rb_at_br(v, c + 1);
            g[k + 1] = f_g_at_rb(v, c + 1);
            bb[k + 1] = v[2][c + 1];
        }
    }

    float* o = out + (size_t)b * 3 * plane + (size_t)y * W + x0;
    *(float4*)(o)     = make_float4(clip01(r[0]), clip01(r[1]), clip01(r[2]), clip01(r[3]));
    *(float4*)(o + 4) = make_float4(clip01(r[4]), clip01(r[5]), clip01(r[6]), clip01(r[7]));
    float* og = o + plane;
    *(float4*)(og)     = make_float4(clip01(g[0]), clip01(g[1]), clip01(g[2]), clip01(g[3]));
    *(float4*)(og + 4) = make_float4(clip01(g[4]), clip01(g[5]), clip01(g[6]), clip01(g[7]));
    float* ob = o + 2 * plane;
    *(float4*)(ob)     = make_float4(clip01(bb[0]), clip01(bb[1]), clip01(bb[2]), clip01(bb[3]));
    *(float4*)(ob + 4) = make_float4(clip01(bb[4]), clip01(bb[5]), clip01(bb[6]), clip01(bb[7]));
}

extern "C" void kernel_launch(void* const* d_in, const int* in_sizes, int n_in,
                              void* d_out, int out_size, void* d_ws, size_t ws_size,
                              hipStream_t stream) {
    const float* bayer = (const float*)d_in[0];
    float* out = (float*)d_out;

    const int H = 2048, W = 2048;
    const int B = in_sizes[0] / (H * W);

    // one block per row: 256 threads x 8 px = 2048 = W
    dim3 block(256, 1, 1);
    dim3 grid(H * B, 1, 1);
    demosaic_kernel<<<grid, block, 0, stream>>>(bayer, out, H, W);
}